// Round 10
// baseline (1016.312 us; speedup 1.0000x reference)
//
#include <hip/hip_runtime.h>

typedef __attribute__((ext_vector_type(8))) short short8;   // 8 x bf16
typedef __attribute__((ext_vector_type(4))) short short4v;  // 4 x bf16
typedef __attribute__((ext_vector_type(4))) float f32x4;

__device__ __forceinline__ float lrelu_f(float v) { return v > 0.f ? v : 0.01f * v; }
__device__ __forceinline__ short f2bf(float f) {
    unsigned u = __float_as_uint(f);
    return (short)((u + 0x7FFFu + ((u >> 16) & 1u)) >> 16);    // RNE
}
__device__ __forceinline__ float bf2f(unsigned short h) {
    return __uint_as_float(((unsigned)h) << 16);
}
// permuted channel pos p = (c&15)*4 + (c>>4); inverse p -> true channel:
__device__ __forceinline__ int p2t(int p) { return ((p & 3) << 4) | (p >> 2); }

// weight fragment emit: dst layout ((k*4+ct)*KS+kk)*512 + lane*8 + r
__device__ __forceinline__ void emit_frag(const float* __restrict__ src, short* __restrict__ dst,
                                          int j, int KS, int permIn)
{
    int r = j & 7, lane = (j >> 3) & 63, rem = j >> 9;
    int kk = (KS == 2) ? (rem & 1) : 0;
    rem = (KS == 2) ? (rem >> 1) : rem;
    int ct = rem & 3, k = rem >> 2;
    int cinf = kk * 32 + ((lane >> 4) << 3) + r;     // fragment-space cin
    int cin = permIn ? p2t(cinf) : cinf;             // true cin in source W
    int cout = ct * 16 + (lane & 15);
    int CIN = KS * 32;
    dst[j] = f2bf(src[(size_t)k * CIN * 64 + (size_t)cin * 64 + cout]);
}

// converts: x + 5 plain bf16 weights (fallback path) + 5 fragment-layout weights
__global__ __launch_bounds__(256) void convert_all(
    const float* __restrict__ x,  short* __restrict__ xb,  int nx,
    const float* __restrict__ W1, short* __restrict__ W1b,  short* __restrict__ W1f,  int n1,  int f1,
    const float* __restrict__ W12,short* __restrict__ W12b, short* __restrict__ W12f, int n12, int f12,
    const float* __restrict__ W2, short* __restrict__ W2b,  short* __restrict__ W2f,  int n2,  int f2,
    const float* __restrict__ W3, short* __restrict__ W3b,  short* __restrict__ W3f,  int n3,  int f3,
    const float* __restrict__ Wp, short* __restrict__ Wpb,  short* __restrict__ Wpf,  int np,  int fp)
{
    const int total = nx + n1 + n12 + n2 + n3 + np + f1 + f12 + f2 + f3 + fp;
    for (int i = blockIdx.x * 256 + threadIdx.x; i < total; i += gridDim.x * 256) {
        int j = i;
        if (j < nx)  { xb[j]   = f2bf(x[j]);   continue; } j -= nx;
        if (j < n1)  { W1b[j]  = f2bf(W1[j]);  continue; } j -= n1;
        if (j < n12) { W12b[j] = f2bf(W12[j]); continue; } j -= n12;
        if (j < n2)  { W2b[j]  = f2bf(W2[j]);  continue; } j -= n2;
        if (j < n3)  { W3b[j]  = f2bf(W3[j]);  continue; } j -= n3;
        if (j < np)  { Wpb[j]  = f2bf(Wp[j]);  continue; } j -= np;
        if (j < f1)  { emit_frag(W1,  W1f,  j, 1, 0); continue; } j -= f1;
        if (j < f12) { emit_frag(W12, W12f, j, 2, 1); continue; } j -= f12;
        if (j < f2)  { emit_frag(W2,  W2f,  j, 1, 0); continue; } j -= f2;
        if (j < f3)  { emit_frag(W3,  W3f,  j, 2, 1); continue; } j -= f3;
        emit_frag(Wp, Wpf, j, 2, 1);
    }
}

// slot reservation for all 3 rulebooks in one dispatch; coalesced pos writes.
// Pool counts are per-chunk: Cp[c][o], chunk c from entry's k.
__global__ __launch_bounds__(256) void reserve3(
    const int* __restrict__ ia, int Ea, int* __restrict__ Ca, int* __restrict__ posA, int BA,
    const int* __restrict__ ib, int Eb, int* __restrict__ Cb, int* __restrict__ posB, int BB,
    const int* __restrict__ ip, int Ep, int* __restrict__ Cp, int* __restrict__ posP,
    int P, int M, int k1, int k2, int k3)
{
    const int b = blockIdx.x;
    if (b < BA + BB) {
        const int* io; int E; int* C; int* pos; int lb;
        if (b < BA) { io = ia; E = Ea; C = Ca; pos = posA; lb = b; }
        else        { io = ib; E = Eb; C = Cb; pos = posB; lb = b - BA; }
        const int e0 = lb * 2048 + threadIdx.x * 8;
        if (e0 >= E) return;
        if (e0 + 8 <= E) {
            int4 v0 = *(const int4*)(io + e0);
            int4 v1 = *(const int4*)(io + e0 + 4);
            int o[8] = {v0.x, v0.y, v0.z, v0.w, v1.x, v1.y, v1.z, v1.w};
            int p[8];
            #pragma unroll
            for (int j = 0; j < 8; ++j) p[j] = atomicAdd(&C[o[j]], 1);
            int4 r0 = {p[0], p[1], p[2], p[3]}, r1 = {p[4], p[5], p[6], p[7]};
            *(int4*)(pos + e0) = r0;
            *(int4*)(pos + e0 + 4) = r1;
        } else {
            for (int e = e0; e < E && e < e0 + 8; ++e)
                pos[e] = atomicAdd(&C[io[e]], 1);
        }
    } else {
        const int lb = b - BA - BB;
        const int e0 = lb * 2048 + threadIdx.x * 8;
        if (e0 >= Ep) return;
        #pragma unroll
        for (int j = 0; j < 8; ++j) {
            int e = e0 + j;
            if (e < Ep) {
                int o = ip[e];
                int k = e / P;
                int c = (k >= k3) ? 3 : (k >= k2) ? 2 : (k >= k1) ? 1 : 0;
                posP[e] = atomicAdd(&Cp[c * M + o], 1);
            }
        }
    }
}

// slot-direct conv, no LDS, pos precomputed. y stored in permuted channel
// order p=col*4+ct (one 8B short4 store per lane per output row quarter).
// Overflow -> f32 atomics into outAcc (permuted space unless OVF_TRUE).
template<int CIN, bool OVF_TRUE>
__global__ __launch_bounds__(256) void spconv_slot(
    const short* __restrict__ feats,   // [N_in, CIN] bf16 (conv space)
    const short* __restrict__ Wf,      // fragment layout
    const int*   __restrict__ iin,
    const int*   __restrict__ iout,
    const int*   __restrict__ pos,
    int P, int kLo, int kHi, int tilesPerK, int wavesPerK, int TPW,
    int cap, short* __restrict__ yslot, float* __restrict__ outAcc)
{
    constexpr int KS = CIN / 32;
    const int lane = threadIdx.x & 63;
    int wid = blockIdx.x * 4 + (threadIdx.x >> 6);
    wid = __builtin_amdgcn_readfirstlane(wid);
    const int k = kLo + wid / wavesPerK;
    if (k >= kHi) return;
    const int wslot = wid % wavesPerK;
    int t0 = wslot * TPW;
    if (t0 >= tilesPerK) return;
    const int t1 = (t0 + TPW < tilesPerK) ? t0 + TPW : tilesPerK;
    const int kBase = k * P, kEnd = kBase + P;
    const int col = lane & 15, g = lane >> 4;

    // B fragments: coalesced 16B loads
    short8 bf[KS][4];
    const short* wkf = Wf + (size_t)k * 4 * KS * 512;
    #pragma unroll
    for (int ct = 0; ct < 4; ++ct)
        #pragma unroll
        for (int kk = 0; kk < KS; ++kk)
            bf[kk][ct] = *(const short8*)(wkf + ((size_t)(ct * KS + kk) << 9) + lane * 8);

    for (int t = t0; t < t1; ++t) {
        const int base = kBase + t * 16;
        int rr = -1, pp = 0;
        if (lane < 16) {
            int ee = base + lane;
            if (ee < kEnd) { rr = iout[ee]; pp = pos[ee]; }
        }
        int ein = base + col;
        if (ein >= kEnd) ein = kEnd - 1;
        const int rin = iin[ein];
        short8 af[KS];
        const short* fr = feats + (size_t)rin * CIN + g * 8;
        #pragma unroll
        for (int kk = 0; kk < KS; ++kk)
            af[kk] = *(const short8*)(fr + kk * 32);

        f32x4 acc[4] = {f32x4{0,0,0,0}, f32x4{0,0,0,0}, f32x4{0,0,0,0}, f32x4{0,0,0,0}};
        #pragma unroll
        for (int kk = 0; kk < KS; ++kk)
            #pragma unroll
            for (int ct = 0; ct < 4; ++ct)
                acc[ct] = __builtin_amdgcn_mfma_f32_16x16x32_bf16(af[kk], bf[kk][ct], acc[ct], 0, 0, 0);

        // C row (entry in tile) = g*4+j; channel = ct*16+col -> perm pos col*4+ct
        #pragma unroll
        for (int j = 0; j < 4; ++j) {
            const int er = base + g * 4 + j;
            const int r2 = __shfl(rr, g * 4 + j);
            const int p2 = __shfl(pp, g * 4 + j);
            if (er < kEnd && r2 >= 0) {
                if (p2 < cap) {
                    short4v v = { f2bf(acc[0][j]), f2bf(acc[1][j]), f2bf(acc[2][j]), f2bf(acc[3][j]) };
                    *(short4v*)(yslot + ((size_t)r2 * cap + p2) * 64 + col * 4) = v;
                } else {
                    float* op = outAcc + (size_t)r2 * 64;
                    #pragma unroll
                    for (int ct = 0; ct < 4; ++ct)
                        atomicAdd(op + (OVF_TRUE ? ct * 16 + col : col * 4 + ct), acc[ct][j]);
                }
            }
        }
    }
}

// contiguous slot-window reduce; accumulates into out (pre-zeroed + overflow).
// UNPERM maps stored position -> true channel for final outputs.
template<bool UNPERM>
__global__ __launch_bounds__(256) void reduce_slot(
    const short* __restrict__ yslot, const int* __restrict__ C, int cap,
    float* __restrict__ out, int nRows)
{
    const int lane = threadIdx.x & 63;
    const int r = blockIdx.x * 4 + (threadIdx.x >> 6);
    if (r >= nRows) return;
    int cnt = C[r]; if (cnt > cap) cnt = cap;
    const unsigned short* basep = (const unsigned short*)yslot + (size_t)r * cap * 64 + lane;
    float a0 = 0.f, a1 = 0.f, a2 = 0.f, a3 = 0.f;
    int s = 0;
    for (; s + 4 <= cnt; s += 4) {
        a0 += bf2f(basep[(s + 0) * 64]);
        a1 += bf2f(basep[(s + 1) * 64]);
        a2 += bf2f(basep[(s + 2) * 64]);
        a3 += bf2f(basep[(s + 3) * 64]);
    }
    for (; s < cnt; ++s) a0 += bf2f(basep[s * 64]);
    const int op_c = UNPERM ? p2t(lane) : lane;
    float* op = out + (size_t)r * 64 + op_c;
    *op = *op + ((a0 + a1) + (a2 + a3));
}

__global__ __launch_bounds__(256) void bn_stats(
    const float* __restrict__ A, int n, float* __restrict__ stats)
{
    __shared__ float ls[256], lq[256];
    float s = 0.f, q = 0.f;
    const long total = (long)n * 64;
    const long stride = (long)gridDim.x * 256;
    for (long i = (long)blockIdx.x * 256 + threadIdx.x; i < total; i += stride) {
        float v = lrelu_f(A[i]);
        s += v; q += v * v;
    }
    ls[threadIdx.x] = s; lq[threadIdx.x] = q;
    __syncthreads();
    if (threadIdx.x < 64) {
        atomicAdd(&stats[threadIdx.x],
                  ls[threadIdx.x] + ls[threadIdx.x + 64] + ls[threadIdx.x + 128] + ls[threadIdx.x + 192]);
        atomicAdd(&stats[64 + threadIdx.x],
                  lq[threadIdx.x] + lq[threadIdx.x + 64] + lq[threadIdx.x + 128] + lq[threadIdx.x + 192]);
    }
}

// r = bn(lrelu(A)) (+ bf16 addsrc in A's space). perm=1: A/addsrc/out_bf are
// permuted-channel; gamma/beta/out_f32 are true-channel.
__global__ __launch_bounds__(256) void bn_apply(
    const float* __restrict__ A, const float* __restrict__ stats,
    const float* __restrict__ gamma, const float* __restrict__ beta,
    const short* __restrict__ addsrc,
    float* __restrict__ out_f32, short* __restrict__ out_bf, int n, int perm)
{
    const int c = threadIdx.x & 63;
    const int tc = perm ? p2t(c) : c;
    const float inv_n = 1.0f / (float)n;
    const float m   = stats[c] * inv_n;
    const float var = stats[64 + c] * inv_n - m * m;
    const float sc  = rsqrtf(var + 1e-5f) * gamma[tc];
    const float bb  = beta[tc] - m * sc;
    const long total = (long)n * 64;
    const long stride = (long)gridDim.x * blockDim.x;
    for (long i = (long)blockIdx.x * blockDim.x + threadIdx.x; i < total; i += stride) {
        float r = lrelu_f(A[i]) * sc + bb;
        if (addsrc) r += bf2f(((const unsigned short*)addsrc)[i]);
        if (out_f32) out_f32[(i & ~63L) + tc] = r;
        if (out_bf)  out_bf[i] = f2bf(r);
    }
}

// ---------------- atomic fallback (ws guard; plain layouts) ----------------
template<int CIN>
__global__ __launch_bounds__(256) void spconv_mfma(
    const short* __restrict__ feats, const short* __restrict__ W,
    const int* __restrict__ iin, const int* __restrict__ iout,
    int P, int tilesPerK, int wavesPerK, int K, int TPW,
    float* __restrict__ out)
{
    constexpr int KS = CIN / 32;
    const int lane = threadIdx.x & 63;
    int wid = blockIdx.x * 4 + (threadIdx.x >> 6);
    wid = __builtin_amdgcn_readfirstlane(wid);
    const int k = wid / wavesPerK;
    if (k >= K) return;
    const int wslot = wid % wavesPerK;
    int t0 = wslot * TPW;
    if (t0 >= tilesPerK) return;
    const int t1 = (t0 + TPW < tilesPerK) ? t0 + TPW : tilesPerK;
    const int kBase = k * P, kEnd = kBase + P;
    const int col = lane & 15, g = lane >> 4;
    short8 bf[KS][4];
    const short* wk = W + (size_t)k * CIN * 64;
    #pragma unroll
    for (int kk = 0; kk < KS; ++kk)
        #pragma unroll
        for (int ct = 0; ct < 4; ++ct)
            #pragma unroll
            for (int r = 0; r < 8; ++r)
                bf[kk][ct][r] = wk[(size_t)(kk * 32 + g * 8 + r) * 64 + ct * 16 + col];
    for (int t = t0; t < t1; ++t) {
        const int base = kBase + t * 16;
        int ein = base + col;
        if (ein >= kEnd) ein = kEnd - 1;
        const int rin = iin[ein];
        short8 af[KS];
        const short* fr = feats + (size_t)rin * CIN + g * 8;
        #pragma unroll
        for (int kk = 0; kk < KS; ++kk)
            af[kk] = *(const short8*)(fr + kk * 32);
        f32x4 acc[4] = {f32x4{0,0,0,0}, f32x4{0,0,0,0}, f32x4{0,0,0,0}, f32x4{0,0,0,0}};
        #pragma unroll
        for (int kk = 0; kk < KS; ++kk)
            #pragma unroll
            for (int ct = 0; ct < 4; ++ct)
                acc[ct] = __builtin_amdgcn_mfma_f32_16x16x32_bf16(af[kk], bf[kk][ct], acc[ct], 0, 0, 0);
        const int rbase = base + g * 4;
        #pragma unroll
        for (int j = 0; j < 4; ++j) {
            const int er = rbase + j;
            if (er < kEnd) {
                const int rout = iout[er];
                float* op = out + (size_t)rout * 64 + col;
                #pragma unroll
                for (int ct = 0; ct < 4; ++ct)
                    atomicAdd(op + ct * 16, acc[ct][j]);
            }
        }
    }
}

extern "C" void kernel_launch(void* const* d_in, const int* in_sizes, int n_in,
                              void* d_out, int out_size, void* d_ws, size_t ws_size,
                              hipStream_t stream)
{
    const float* x   = (const float*)d_in[0];
    const float* W1  = (const float*)d_in[1];
    const float* W12 = (const float*)d_in[2];
    const float* W2  = (const float*)d_in[3];
    const float* W3  = (const float*)d_in[4];
    const float* Wp  = (const float*)d_in[5];
    const float* g0  = (const float*)d_in[6];
    const float* b0  = (const float*)d_in[7];
    const float* g02 = (const float*)d_in[8];
    const float* b02 = (const float*)d_in[9];
    const float* g1  = (const float*)d_in[10];
    const float* b1  = (const float*)d_in[11];
    const float* g2  = (const float*)d_in[12];
    const float* b2  = (const float*)d_in[13];
    const int* rb_a_in  = (const int*)d_in[14];
    const int* rb_a_out = (const int*)d_in[15];
    const int* rb_b_in  = (const int*)d_in[16];
    const int* rb_b_out = (const int*)d_in[17];
    const int* rb_p_in  = (const int*)d_in[18];
    const int* rb_p_out = (const int*)d_in[19];

    const int N  = in_sizes[0] / 32;
    const int M  = out_size / 64 - N;
    const int Ea = in_sizes[14];
    const int Eb = in_sizes[16];
    const int Ep = in_sizes[18];
    const int Ka = Ea / N, Kp = Ep / N;   // 9, 27
    const int P  = N;

    float* resB = (float*)d_out;
    float* resA = resB + (size_t)M * 64;

    // fragment sizes (elements)
    const int f1  = 9 * 4 * 1 * 512, f12 = 9 * 4 * 2 * 512;
    const int f2s = 9 * 4 * 1 * 512, f3  = 9 * 4 * 2 * 512, fp = 27 * 4 * 2 * 512;

    // ---- workspace layout ----
    size_t off = 0;
    auto take = [&](size_t bytes) { size_t o = off; off += (bytes + 255) & ~(size_t)255; return o; };
    char* base = (char*)d_ws;
    size_t oA    = take((size_t)N * 64 * 4);      // f32 accumulator (+overflow target)
    size_t oBbf  = take((size_t)N * 64 * 2);      // bf16 shortcut (perm space)
    size_t oxb   = take((size_t)N * 32 * 2);
    size_t otb   = take((size_t)N * 64 * 2);
    size_t oW1   = take((size_t)9 * 32 * 64 * 2);
    size_t oW12  = take((size_t)9 * 64 * 64 * 2);
    size_t oW2   = take((size_t)9 * 32 * 64 * 2);
    size_t oW3   = take((size_t)9 * 64 * 64 * 2);
    size_t oWp   = take((size_t)27 * 64 * 64 * 2);
    size_t oW1f  = take((size_t)f1 * 2);
    size_t oW12f = take((size_t)f12 * 2);
    size_t oW2f  = take((size_t)f2s * 2);
    size_t oW3f  = take((size_t)f3 * 2);
    size_t oWpf  = take((size_t)fp * 2);
    size_t oPa   = take((size_t)Ea * 4);
    size_t oPb   = take((size_t)Eb * 4);
    size_t oPp   = take((size_t)Ep * 4);
    size_t oCNT  = take(((size_t)2 * N + 4 * M + 512) * 4);  // Ca | Cb | Cp[4][M] | stats[512]
    const size_t oDyn = off;

    float* A     = (float*)(base + oA);
    short* B_bf  = (short*)(base + oBbf);
    short* x_bf  = (short*)(base + oxb);
    short* t_bf  = (short*)(base + otb);
    short* W1b   = (short*)(base + oW1);
    short* W12b  = (short*)(base + oW12);
    short* W2b   = (short*)(base + oW2);
    short* W3b   = (short*)(base + oW3);
    short* Wpb   = (short*)(base + oWp);
    short* W1f   = (short*)(base + oW1f);
    short* W12f  = (short*)(base + oW12f);
    short* W2f   = (short*)(base + oW2f);
    short* W3f   = (short*)(base + oW3f);
    short* Wpf   = (short*)(base + oWpf);
    int*   pos_a = (int*)(base + oPa);
    int*   pos_b = (int*)(base + oPb);
    int*   pos_p = (int*)(base + oPp);
    int*   Cbase = (int*)(base + oCNT);
    int*   Ca    = Cbase;
    int*   Cb    = Cbase + N;
    int*   Cp    = Cbase + 2 * N;                 // [4][M]
    float* stats = (float*)(Cbase + 2 * N + 4 * M);
    short* yslot = (short*)(base + oDyn);

    const size_t avail = (ws_size > oDyn) ? (ws_size - oDyn) : 0;
    long cA = (long)(avail / ((size_t)N * 128));
    long cP = (long)(avail / ((size_t)M * 128));
    const int capAB = (int)(cA < 16 ? cA : 16);
    const int capP  = (int)(cP < 40 ? cP : 40);

    dim3 blk(256);
    const int tilesPerK = (P + 15) / 16;
    const int TPW = 4;
    const int wavesPerK = (tilesPerK + TPW - 1) / TPW;
    auto gWaves = [&](int nk) { return dim3((unsigned)((nk * wavesPerK + 3) / 4)); };
    auto gRows  = [](int nr) { return dim3((unsigned)((nr + 3) / 4)); };
    const int nx = N * 32, n1 = 9*32*64, n12 = 9*64*64, n2 = 9*32*64, n3 = 9*64*64, np = 27*64*64;
    const size_t fbytes = (size_t)N * 64 * sizeof(float);
    const int k1 = (Kp + 3) / 4, k2 = (2 * Kp + 3) / 4, k3 = (3 * Kp + 3) / 4;

    convert_all<<<1024, blk, 0, stream>>>(
        x, x_bf, nx,
        W1, W1b, W1f, n1, f1,  W12, W12b, W12f, n12, f12,
        W2, W2b, W2f, n2, f2s, W3, W3b, W3f, n3, f3,
        Wp, Wpb, Wpf, np, fp);
    hipMemsetAsync(Cbase, 0, ((size_t)2 * N + 4 * M + 512) * 4, stream);

    if (capAB >= 8 && capP >= 24) {
        const int BA = (Ea + 2047) / 2048, BB = (Eb + 2047) / 2048, BP = (Ep + 2047) / 2048;
        reserve3<<<dim3((unsigned)(BA + BB + BP)), blk, 0, stream>>>(
            rb_a_out, Ea, Ca, pos_a, BA,
            rb_b_out, Eb, Cb, pos_b, BB,
            rb_p_out, Ep, Cp, pos_p, P, M, k1, k2, k3);

        float* st0 = stats, *st1 = stats + 128, *st2 = stats + 256, *st3 = stats + 384;

        // conv1 (rb_a, 32->64) -> A(perm) ; bn -> t_bf(perm)
        hipMemsetAsync(A, 0, fbytes, stream);
        spconv_slot<32, false><<<gWaves(Ka), blk, 0, stream>>>(x_bf, W1f, rb_a_in, rb_a_out, pos_a, P, 0, Ka, tilesPerK, wavesPerK, TPW, capAB, yslot, A);
        reduce_slot<false><<<gRows(N), blk, 0, stream>>>(yslot, Ca, capAB, A, N);
        bn_stats<<<256, blk, 0, stream>>>(A, N, st0);
        bn_apply<<<512, blk, 0, stream>>>(A, st0, g0, b0, nullptr, nullptr, t_bf, N, 1);

        // conv1_2 (rb_b, 64->64) -> A ; bn -> B_bf(perm)
        hipMemsetAsync(A, 0, fbytes, stream);
        spconv_slot<64, false><<<gWaves(Ka), blk, 0, stream>>>(t_bf, W12f, rb_b_in, rb_b_out, pos_b, P, 0, Ka, tilesPerK, wavesPerK, TPW, capAB, yslot, A);
        reduce_slot<false><<<gRows(N), blk, 0, stream>>>(yslot, Cb, capAB, A, N);
        bn_stats<<<256, blk, 0, stream>>>(A, N, st1);
        bn_apply<<<512, blk, 0, stream>>>(A, st1, g02, b02, nullptr, nullptr, B_bf, N, 1);

        // conv2 (rb_b, 32->64) -> A ; bn -> t_bf(perm)
        hipMemsetAsync(A, 0, fbytes, stream);
        spconv_slot<32, false><<<gWaves(Ka), blk, 0, stream>>>(x_bf, W2f, rb_b_in, rb_b_out, pos_b, P, 0, Ka, tilesPerK, wavesPerK, TPW, capAB, yslot, A);
        reduce_slot<false><<<gRows(N), blk, 0, stream>>>(yslot, Cb, capAB, A, N);
        bn_stats<<<256, blk, 0, stream>>>(A, N, st2);
        bn_apply<<<512, blk, 0, stream>>>(A, st2, g1, b1, nullptr, nullptr, t_bf, N, 1);

        // conv3 (rb_a, 64->64) -> A ; bn + shortcut -> resA(true) + t_bf(perm)
        hipMemsetAsync(A, 0, fbytes, stream);
        spconv_slot<64, false><<<gWaves(Ka), blk, 0, stream>>>(t_bf, W3f, rb_a_in, rb_a_out, pos_a, P, 0, Ka, tilesPerK, wavesPerK, TPW, capAB, yslot, A);
        reduce_slot<false><<<gRows(N), blk, 0, stream>>>(yslot, Ca, capAB, A, N);
        bn_stats<<<256, blk, 0, stream>>>(A, N, st3);
        bn_apply<<<512, blk, 0, stream>>>(A, st3, g2, b2, B_bf, resA, t_bf, N, 1);

        // pool conv (rb_p, 64->64), 4 k-chunks reusing y window -> resB (true)
        hipMemsetAsync(resB, 0, (size_t)M * 64 * sizeof(float), stream);
        const int kc[5] = {0, k1, k2, k3, Kp};
        for (int c = 0; c < 4; ++c) {
            spconv_slot<64, true><<<gWaves(kc[c + 1] - kc[c]), blk, 0, stream>>>(t_bf, Wpf, rb_p_in, rb_p_out, pos_p, P, kc[c], kc[c + 1], tilesPerK, wavesPerK, TPW, capP, yslot, resB);
            reduce_slot<true><<<gRows(M), blk, 0, stream>>>(yslot, Cp + c * M, capP, resB, M);
        }
    } else {
        // -------- atomic fallback (true space everywhere) --------
        const int TPW2 = 16;
        const int wPK = (tilesPerK + TPW2 - 1) / TPW2;
        auto cblocks = [&](int K) { return dim3((unsigned)((K * wPK + 3) / 4)); };
        float* st = stats;

        hipMemsetAsync(A, 0, fbytes, stream);
        spconv_mfma<32><<<cblocks(Ka), blk, 0, stream>>>(x_bf, W1b, rb_a_in, rb_a_out, P, tilesPerK, wPK, Ka, TPW2, A);
        bn_stats<<<256, blk, 0, stream>>>(A, N, st);
        bn_apply<<<512, blk, 0, stream>>>(A, st, g0, b0, nullptr, nullptr, t_bf, N, 0);

        hipMemsetAsync(A, 0, fbytes, stream);
        spconv_mfma<64><<<cblocks(Ka), blk, 0, stream>>>(t_bf, W12b, rb_b_in, rb_b_out, P, tilesPerK, wPK, Ka, TPW2, A);
        bn_stats<<<256, blk, 0, stream>>>(A, N, st + 128);
        bn_apply<<<512, blk, 0, stream>>>(A, st + 128, g02, b02, nullptr, nullptr, B_bf, N, 0);

        hipMemsetAsync(A, 0, fbytes, stream);
        spconv_mfma<32><<<cblocks(Ka), blk, 0, stream>>>(x_bf, W2b, rb_b_in, rb_b_out, P, tilesPerK, wPK, Ka, TPW2, A);
        bn_stats<<<256, blk, 0, stream>>>(A, N, st + 256);
        bn_apply<<<512, blk, 0, stream>>>(A, st + 256, g1, b1, nullptr, nullptr, t_bf, N, 0);

        hipMemsetAsync(resA, 0, fbytes, stream);
        spconv_mfma<64><<<cblocks(Ka), blk, 0, stream>>>(t_bf, W3b, rb_a_in, rb_a_out, P, tilesPerK, wPK, Ka, TPW2, resA);
        bn_stats<<<256, blk, 0, stream>>>(resA, N, st + 384);
        bn_apply<<<512, blk, 0, stream>>>(resA, st + 384, g2, b2, B_bf, resA, t_bf, N, 0);

        hipMemsetAsync(resB, 0, (size_t)M * 64 * sizeof(float), stream);
        spconv_mfma<64><<<cblocks(Kp), blk, 0, stream>>>(t_bf, Wpb, rb_p_in, rb_p_out, P, tilesPerK, wPK, Kp, TPW2, resB);
    }
}

// Round 11
// 969.123 us; speedup vs baseline: 1.0487x; 1.0487x over previous
//
#include <hip/hip_runtime.h>

typedef __attribute__((ext_vector_type(8))) short short8;   // 8 x bf16
typedef __attribute__((ext_vector_type(4))) short short4v;  // 4 x bf16
typedef __attribute__((ext_vector_type(4))) float f32x4;

__device__ __forceinline__ float lrelu_f(float v) { return v > 0.f ? v : 0.01f * v; }
__device__ __forceinline__ short f2bf(float f) {
    unsigned u = __float_as_uint(f);
    return (short)((u + 0x7FFFu + ((u >> 16) & 1u)) >> 16);    // RNE
}
__device__ __forceinline__ float bf2f(unsigned short h) {
    return __uint_as_float(((unsigned)h) << 16);
}
// permuted channel pos p = (c&15)*4 + (c>>4); inverse p -> true channel:
__device__ __forceinline__ int p2t(int p) { return ((p & 3) << 4) | (p >> 2); }

// weight fragment emit: dst layout ((k*4+ct)*KS+kk)*512 + lane*8 + r
__device__ __forceinline__ void emit_frag(const float* __restrict__ src, short* __restrict__ dst,
                                          int j, int KS, int permIn)
{
    int r = j & 7, lane = (j >> 3) & 63, rem = j >> 9;
    int kk = (KS == 2) ? (rem & 1) : 0;
    rem = (KS == 2) ? (rem >> 1) : rem;
    int ct = rem & 3, k = rem >> 2;
    int cinf = kk * 32 + ((lane >> 4) << 3) + r;     // fragment-space cin
    int cin = permIn ? p2t(cinf) : cinf;             // true cin in source W
    int cout = ct * 16 + (lane & 15);
    int CIN = KS * 32;
    dst[j] = f2bf(src[(size_t)k * CIN * 64 + (size_t)cin * 64 + cout]);
}

// slot reservation worker: blocks of 2048 entries in [eLo, eHi).
// mode 1: flat counters C[o]; mode 2: pool-chunked C[chunk(k)*M + o].
__device__ __forceinline__ void do_reserve(
    const int* __restrict__ io, int eLo, int eHi,
    int* __restrict__ C, int* __restrict__ pos, int lb,
    int mode, int P, int M, int k1, int k2, int k3)
{
    const int e0 = eLo + lb * 2048 + (int)threadIdx.x * 8;
    if (e0 >= eHi) return;
    if (mode == 1 && e0 + 8 <= eHi) {
        int4 v0 = *(const int4*)(io + e0);
        int4 v1 = *(const int4*)(io + e0 + 4);
        int o[8] = {v0.x, v0.y, v0.z, v0.w, v1.x, v1.y, v1.z, v1.w};
        int p[8];
        #pragma unroll
        for (int j = 0; j < 8; ++j) p[j] = atomicAdd(&C[o[j]], 1);
        int4 r0 = {p[0], p[1], p[2], p[3]}, r1 = {p[4], p[5], p[6], p[7]};
        *(int4*)(pos + e0) = r0;
        *(int4*)(pos + e0 + 4) = r1;
    } else {
        for (int e = e0; e < eHi && e < e0 + 8; ++e) {
            int o = io[e];
            int* cp;
            if (mode == 2) {
                int k = e / P;
                int c = (k >= k3) ? 3 : (k >= k2) ? 2 : (k >= k1) ? 1 : 0;
                cp = &C[c * M + o];
            } else {
                cp = &C[o];
            }
            pos[e] = atomicAdd(cp, 1);
        }
    }
}

// converts (blocks < CB) + rb_a reservation (blocks >= CB)
__global__ __launch_bounds__(256) void prep(
    const float* __restrict__ x,  short* __restrict__ xb,  int nx,
    const float* __restrict__ W1, short* __restrict__ W1b,  short* __restrict__ W1f,  int n1,  int f1,
    const float* __restrict__ W12,short* __restrict__ W12b, short* __restrict__ W12f, int n12, int f12,
    const float* __restrict__ W2, short* __restrict__ W2b,  short* __restrict__ W2f,  int n2,  int f2,
    const float* __restrict__ W3, short* __restrict__ W3b,  short* __restrict__ W3f,  int n3,  int f3,
    const float* __restrict__ Wp, short* __restrict__ Wpb,  short* __restrict__ Wpf,  int np,  int fp,
    int CB,
    const int* __restrict__ ria, int rEa, int* __restrict__ rCa, int* __restrict__ rposA)
{
    if ((int)blockIdx.x >= CB) {
        if (ria) do_reserve(ria, 0, rEa, rCa, rposA, blockIdx.x - CB, 1, 0, 0, 0, 0, 0);
        return;
    }
    const int total = nx + n1 + n12 + n2 + n3 + np + f1 + f12 + f2 + f3 + fp;
    for (int i = blockIdx.x * 256 + threadIdx.x; i < total; i += CB * 256) {
        int j = i;
        if (j < nx)  { xb[j]   = f2bf(x[j]);   continue; } j -= nx;
        if (j < n1)  { W1b[j]  = f2bf(W1[j]);  continue; } j -= n1;
        if (j < n12) { W12b[j] = f2bf(W12[j]); continue; } j -= n12;
        if (j < n2)  { W2b[j]  = f2bf(W2[j]);  continue; } j -= n2;
        if (j < n3)  { W3b[j]  = f2bf(W3[j]);  continue; } j -= n3;
        if (j < np)  { Wpb[j]  = f2bf(Wp[j]);  continue; } j -= np;
        if (j < f1)  { emit_frag(W1,  W1f,  j, 1, 0); continue; } j -= f1;
        if (j < f12) { emit_frag(W12, W12f, j, 2, 1); continue; } j -= f12;
        if (j < f2)  { emit_frag(W2,  W2f,  j, 1, 0); continue; } j -= f2;
        if (j < f3)  { emit_frag(W3,  W3f,  j, 2, 1); continue; } j -= f3;
        emit_frag(Wp, Wpf, j, 2, 1);
    }
}

// slot-direct conv (blocks < convBlocks) + piggybacked reservation (rest).
// y stored in permuted channel order p=col*4+ct; overflow -> f32 atomics.
template<int CIN, bool OVF_TRUE>
__global__ __launch_bounds__(256) void spconv_slot(
    const short* __restrict__ feats,   // [N_in, CIN] bf16 (conv space)
    const short* __restrict__ Wf,      // fragment layout
    const int*   __restrict__ iin,
    const int*   __restrict__ iout,
    const int*   __restrict__ pos,
    int P, int kLo, int kHi, int tilesPerK, int wavesPerK, int TPW,
    int cap, short* __restrict__ yslot, float* __restrict__ outAcc,
    int convBlocks,
    const int* __restrict__ rio, int rLo, int rHi,
    int* __restrict__ rC, int* __restrict__ rpos,
    int rmode, int rM, int rk1, int rk2, int rk3)
{
    if ((int)blockIdx.x >= convBlocks) {
        if (rmode) do_reserve(rio, rLo, rHi, rC, rpos, blockIdx.x - convBlocks,
                              rmode, P, rM, rk1, rk2, rk3);
        return;
    }
    constexpr int KS = CIN / 32;
    const int lane = threadIdx.x & 63;
    int wid = blockIdx.x * 4 + (threadIdx.x >> 6);
    wid = __builtin_amdgcn_readfirstlane(wid);
    const int k = kLo + wid / wavesPerK;
    if (k >= kHi) return;
    const int wslot = wid % wavesPerK;
    int t0 = wslot * TPW;
    if (t0 >= tilesPerK) return;
    const int t1 = (t0 + TPW < tilesPerK) ? t0 + TPW : tilesPerK;
    const int kBase = k * P, kEnd = kBase + P;
    const int col = lane & 15, g = lane >> 4;

    // B fragments: coalesced 16B loads
    short8 bf[KS][4];
    const short* wkf = Wf + (size_t)k * 4 * KS * 512;
    #pragma unroll
    for (int ct = 0; ct < 4; ++ct)
        #pragma unroll
        for (int kk = 0; kk < KS; ++kk)
            bf[kk][ct] = *(const short8*)(wkf + ((size_t)(ct * KS + kk) << 9) + lane * 8);

    for (int t = t0; t < t1; ++t) {
        const int base = kBase + t * 16;
        int rr = -1, pp = 0;
        if (lane < 16) {
            int ee = base + lane;
            if (ee < kEnd) { rr = iout[ee]; pp = pos[ee]; }
        }
        int ein = base + col;
        if (ein >= kEnd) ein = kEnd - 1;
        const int rin = iin[ein];
        short8 af[KS];
        const short* fr = feats + (size_t)rin * CIN + g * 8;
        #pragma unroll
        for (int kk = 0; kk < KS; ++kk)
            af[kk] = *(const short8*)(fr + kk * 32);

        f32x4 acc[4] = {f32x4{0,0,0,0}, f32x4{0,0,0,0}, f32x4{0,0,0,0}, f32x4{0,0,0,0}};
        #pragma unroll
        for (int kk = 0; kk < KS; ++kk)
            #pragma unroll
            for (int ct = 0; ct < 4; ++ct)
                acc[ct] = __builtin_amdgcn_mfma_f32_16x16x32_bf16(af[kk], bf[kk][ct], acc[ct], 0, 0, 0);

        // C row (entry in tile) = g*4+j; channel = ct*16+col -> perm pos col*4+ct
        #pragma unroll
        for (int j = 0; j < 4; ++j) {
            const int er = base + g * 4 + j;
            const int r2 = __shfl(rr, g * 4 + j);
            const int p2 = __shfl(pp, g * 4 + j);
            if (er < kEnd && r2 >= 0) {
                if (p2 < cap) {
                    short4v v = { f2bf(acc[0][j]), f2bf(acc[1][j]), f2bf(acc[2][j]), f2bf(acc[3][j]) };
                    *(short4v*)(yslot + ((size_t)r2 * cap + p2) * 64 + col * 4) = v;
                } else {
                    float* op = outAcc + (size_t)r2 * 64;
                    #pragma unroll
                    for (int ct = 0; ct < 4; ++ct)
                        atomicAdd(op + (OVF_TRUE ? ct * 16 + col : col * 4 + ct), acc[ct][j]);
                }
            }
        }
    }
}

// contiguous slot-window reduce; accumulates into out (pre-zeroed + overflow).
template<bool UNPERM>
__global__ __launch_bounds__(256) void reduce_slot(
    const short* __restrict__ yslot, const int* __restrict__ C, int cap,
    float* __restrict__ out, int nRows)
{
    const int lane = threadIdx.x & 63;
    const int r = blockIdx.x * 4 + (threadIdx.x >> 6);
    if (r >= nRows) return;
    int cnt = C[r]; if (cnt > cap) cnt = cap;
    const unsigned short* basep = (const unsigned short*)yslot + (size_t)r * cap * 64 + lane;
    float a0 = 0.f, a1 = 0.f, a2 = 0.f, a3 = 0.f;
    int s = 0;
    for (; s + 4 <= cnt; s += 4) {
        a0 += bf2f(basep[(s + 0) * 64]);
        a1 += bf2f(basep[(s + 1) * 64]);
        a2 += bf2f(basep[(s + 2) * 64]);
        a3 += bf2f(basep[(s + 3) * 64]);
    }
    for (; s < cnt; ++s) a0 += bf2f(basep[s * 64]);
    const int op_c = UNPERM ? p2t(lane) : lane;
    float* op = out + (size_t)r * 64 + op_c;
    *op = *op + ((a0 + a1) + (a2 + a3));
}

__global__ __launch_bounds__(256) void bn_stats(
    const float* __restrict__ A, int n, float* __restrict__ stats)
{
    __shared__ float ls[256], lq[256];
    float s = 0.f, q = 0.f;
    const long total = (long)n * 64;
    const long stride = (long)gridDim.x * 256;
    for (long i = (long)blockIdx.x * 256 + threadIdx.x; i < total; i += stride) {
        float v = lrelu_f(A[i]);
        s += v; q += v * v;
    }
    ls[threadIdx.x] = s; lq[threadIdx.x] = q;
    __syncthreads();
    if (threadIdx.x < 64) {
        atomicAdd(&stats[threadIdx.x],
                  ls[threadIdx.x] + ls[threadIdx.x + 64] + ls[threadIdx.x + 128] + ls[threadIdx.x + 192]);
        atomicAdd(&stats[64 + threadIdx.x],
                  lq[threadIdx.x] + lq[threadIdx.x + 64] + lq[threadIdx.x + 128] + lq[threadIdx.x + 192]);
    }
}

// r = bn(lrelu(A)) (+ bf16 addsrc in A's space). perm=1: A/addsrc/out_bf are
// permuted-channel; gamma/beta/out_f32 are true-channel.
__global__ __launch_bounds__(256) void bn_apply(
    const float* __restrict__ A, const float* __restrict__ stats,
    const float* __restrict__ gamma, const float* __restrict__ beta,
    const short* __restrict__ addsrc,
    float* __restrict__ out_f32, short* __restrict__ out_bf, int n, int perm)
{
    const int c = threadIdx.x & 63;
    const int tc = perm ? p2t(c) : c;
    const float inv_n = 1.0f / (float)n;
    const float m   = stats[c] * inv_n;
    const float var = stats[64 + c] * inv_n - m * m;
    const float sc  = rsqrtf(var + 1e-5f) * gamma[tc];
    const float bb  = beta[tc] - m * sc;
    const long total = (long)n * 64;
    const long stride = (long)gridDim.x * blockDim.x;
    for (long i = (long)blockIdx.x * blockDim.x + threadIdx.x; i < total; i += stride) {
        float r = lrelu_f(A[i]) * sc + bb;
        if (addsrc) r += bf2f(((const unsigned short*)addsrc)[i]);
        if (out_f32) out_f32[(i & ~63L) + tc] = r;
        if (out_bf)  out_bf[i] = f2bf(r);
    }
}

// ---------------- atomic fallback (ws guard; plain layouts) ----------------
template<int CIN>
__global__ __launch_bounds__(256) void spconv_mfma(
    const short* __restrict__ feats, const short* __restrict__ W,
    const int* __restrict__ iin, const int* __restrict__ iout,
    int P, int tilesPerK, int wavesPerK, int K, int TPW,
    float* __restrict__ out)
{
    constexpr int KS = CIN / 32;
    const int lane = threadIdx.x & 63;
    int wid = blockIdx.x * 4 + (threadIdx.x >> 6);
    wid = __builtin_amdgcn_readfirstlane(wid);
    const int k = wid / wavesPerK;
    if (k >= K) return;
    const int wslot = wid % wavesPerK;
    int t0 = wslot * TPW;
    if (t0 >= tilesPerK) return;
    const int t1 = (t0 + TPW < tilesPerK) ? t0 + TPW : tilesPerK;
    const int kBase = k * P, kEnd = kBase + P;
    const int col = lane & 15, g = lane >> 4;
    short8 bf[KS][4];
    const short* wk = W + (size_t)k * CIN * 64;
    #pragma unroll
    for (int kk = 0; kk < KS; ++kk)
        #pragma unroll
        for (int ct = 0; ct < 4; ++ct)
            #pragma unroll
            for (int r = 0; r < 8; ++r)
                bf[kk][ct][r] = wk[(size_t)(kk * 32 + g * 8 + r) * 64 + ct * 16 + col];
    for (int t = t0; t < t1; ++t) {
        const int base = kBase + t * 16;
        int ein = base + col;
        if (ein >= kEnd) ein = kEnd - 1;
        const int rin = iin[ein];
        short8 af[KS];
        const short* fr = feats + (size_t)rin * CIN + g * 8;
        #pragma unroll
        for (int kk = 0; kk < KS; ++kk)
            af[kk] = *(const short8*)(fr + kk * 32);
        f32x4 acc[4] = {f32x4{0,0,0,0}, f32x4{0,0,0,0}, f32x4{0,0,0,0}, f32x4{0,0,0,0}};
        #pragma unroll
        for (int kk = 0; kk < KS; ++kk)
            #pragma unroll
            for (int ct = 0; ct < 4; ++ct)
                acc[ct] = __builtin_amdgcn_mfma_f32_16x16x32_bf16(af[kk], bf[kk][ct], acc[ct], 0, 0, 0);
        const int rbase = base + g * 4;
        #pragma unroll
        for (int j = 0; j < 4; ++j) {
            const int er = rbase + j;
            if (er < kEnd) {
                const int rout = iout[er];
                float* op = out + (size_t)rout * 64 + col;
                #pragma unroll
                for (int ct = 0; ct < 4; ++ct)
                    atomicAdd(op + ct * 16, acc[ct][j]);
            }
        }
    }
}

extern "C" void kernel_launch(void* const* d_in, const int* in_sizes, int n_in,
                              void* d_out, int out_size, void* d_ws, size_t ws_size,
                              hipStream_t stream)
{
    const float* x   = (const float*)d_in[0];
    const float* W1  = (const float*)d_in[1];
    const float* W12 = (const float*)d_in[2];
    const float* W2  = (const float*)d_in[3];
    const float* W3  = (const float*)d_in[4];
    const float* Wp  = (const float*)d_in[5];
    const float* g0  = (const float*)d_in[6];
    const float* b0  = (const float*)d_in[7];
    const float* g02 = (const float*)d_in[8];
    const float* b02 = (const float*)d_in[9];
    const float* g1  = (const float*)d_in[10];
    const float* b1  = (const float*)d_in[11];
    const float* g2  = (const float*)d_in[12];
    const float* b2  = (const float*)d_in[13];
    const int* rb_a_in  = (const int*)d_in[14];
    const int* rb_a_out = (const int*)d_in[15];
    const int* rb_b_in  = (const int*)d_in[16];
    const int* rb_b_out = (const int*)d_in[17];
    const int* rb_p_in  = (const int*)d_in[18];
    const int* rb_p_out = (const int*)d_in[19];

    const int N  = in_sizes[0] / 32;
    const int M  = out_size / 64 - N;
    const int Ea = in_sizes[14];
    const int Eb = in_sizes[16];
    const int Ep = in_sizes[18];
    const int Ka = Ea / N, Kp = Ep / N;   // 9, 27
    const int P  = N;

    float* resB = (float*)d_out;
    float* resA = resB + (size_t)M * 64;

    // fragment sizes (elements)
    const int f1  = 9 * 4 * 1 * 512, f12 = 9 * 4 * 2 * 512;
    const int f2s = 9 * 4 * 1 * 512, f3  = 9 * 4 * 2 * 512, fp = 27 * 4 * 2 * 512;

    // ---- workspace layout ----
    size_t off = 0;
    auto take = [&](size_t bytes) { size_t o = off; off += (bytes + 255) & ~(size_t)255; return o; };
    char* base = (char*)d_ws;
    size_t oA    = take((size_t)N * 64 * 4);      // f32 accumulator (+overflow target)
    size_t oBbf  = take((size_t)N * 64 * 2);      // bf16 shortcut (perm space)
    size_t oxb   = take((size_t)N * 32 * 2);
    size_t otb   = take((size_t)N * 64 * 2);
    size_t oW1   = take((size_t)9 * 32 * 64 * 2);
    size_t oW12  = take((size_t)9 * 64 * 64 * 2);
    size_t oW2   = take((size_t)9 * 32 * 64 * 2);
    size_t oW3   = take((size_t)9 * 64 * 64 * 2);
    size_t oWp   = take((size_t)27 * 64 * 64 * 2);
    size_t oW1f  = take((size_t)f1 * 2);
    size_t oW12f = take((size_t)f12 * 2);
    size_t oW2f  = take((size_t)f2s * 2);
    size_t oW3f  = take((size_t)f3 * 2);
    size_t oWpf  = take((size_t)fp * 2);
    size_t oPa   = take((size_t)Ea * 4);
    size_t oPb   = take((size_t)Eb * 4);
    size_t oPp   = take((size_t)Ep * 4);
    size_t oCNT  = take(((size_t)2 * N + 4 * M + 512) * 4);  // Ca | Cb | Cp[4][M] | stats[512]
    const size_t oDyn = off;

    float* A     = (float*)(base + oA);
    short* B_bf  = (short*)(base + oBbf);
    short* x_bf  = (short*)(base + oxb);
    short* t_bf  = (short*)(base + otb);
    short* W1b   = (short*)(base + oW1);
    short* W12b  = (short*)(base + oW12);
    short* W2b   = (short*)(base + oW2);
    short* W3b   = (short*)(base + oW3);
    short* Wpb   = (short*)(base + oWp);
    short* W1f   = (short*)(base + oW1f);
    short* W12f  = (short*)(base + oW12f);
    short* W2f   = (short*)(base + oW2f);
    short* W3f   = (short*)(base + oW3f);
    short* Wpf   = (short*)(base + oWpf);
    int*   pos_a = (int*)(base + oPa);
    int*   pos_b = (int*)(base + oPb);
    int*   pos_p = (int*)(base + oPp);
    int*   Cbase = (int*)(base + oCNT);
    int*   Ca    = Cbase;
    int*   Cb    = Cbase + N;
    int*   Cp    = Cbase + 2 * N;                 // [4][M]
    float* stats = (float*)(Cbase + 2 * N + 4 * M);
    short* yslot = (short*)(base + oDyn);

    const size_t avail = (ws_size > oDyn) ? (ws_size - oDyn) : 0;
    long cA = (long)(avail / ((size_t)N * 128));
    long cP = (long)(avail / ((size_t)M * 128));
    const int capAB = (int)(cA < 16 ? cA : 16);
    const int capP  = (int)(cP < 40 ? cP : 40);

    dim3 blk(256);
    const int tilesPerK = (P + 15) / 16;
    const int TPW = 4;
    const int wavesPerK = (tilesPerK + TPW - 1) / TPW;
    auto nConvBlocks = [&](int nk) { return (nk * wavesPerK + 3) / 4; };
    auto gRows  = [](int nr) { return dim3((unsigned)((nr + 3) / 4)); };
    auto rsvBlocks = [](int lo, int hi) { return (hi - lo + 2047) / 2048; };
    const int nx = N * 32, n1 = 9*32*64, n12 = 9*64*64, n2 = 9*32*64, n3 = 9*64*64, np = 27*64*64;
    const size_t fbytes = (size_t)N * 64 * sizeof(float);
    const int k1 = (Kp + 3) / 4, k2 = (2 * Kp + 3) / 4, k3 = (3 * Kp + 3) / 4;

    // pool reserve thirds, 2048-aligned for vector path
    const int s1 = ((Ep / 3) / 2048) * 2048;
    const int s2 = ((2 * Ep / 3) / 2048) * 2048;

    // counters must be zero before any reservation
    hipMemsetAsync(Cbase, 0, ((size_t)2 * N + 4 * M + 512) * 4, stream);

    const bool slotPath = (capAB >= 8 && capP >= 24);
    const int CB = 1024;

    // prep: converts + rb_a reservation
    {
        const int rb = slotPath ? rsvBlocks(0, Ea) : 0;
        prep<<<dim3((unsigned)(CB + rb)), blk, 0, stream>>>(
            x, x_bf, nx,
            W1, W1b, W1f, n1, f1,  W12, W12b, W12f, n12, f12,
            W2, W2b, W2f, n2, f2s, W3, W3b, W3f, n3, f3,
            Wp, Wpb, Wpf, np, fp,
            CB, slotPath ? rb_a_out : nullptr, Ea, Ca, pos_a);
    }

    if (slotPath) {
        float* st0 = stats, *st1 = stats + 128, *st2 = stats + 256, *st3 = stats + 384;
        const int cb = nConvBlocks(Ka);

        // conv1 (rb_a, 32->64) -> A(perm), carries rb_b reservation
        hipMemsetAsync(A, 0, fbytes, stream);
        spconv_slot<32, false><<<dim3((unsigned)(cb + rsvBlocks(0, Eb))), blk, 0, stream>>>(
            x_bf, W1f, rb_a_in, rb_a_out, pos_a, P, 0, Ka, tilesPerK, wavesPerK, TPW, capAB, yslot, A,
            cb, rb_b_out, 0, Eb, Cb, pos_b, 1, M, 0, 0, 0);
        reduce_slot<false><<<gRows(N), blk, 0, stream>>>(yslot, Ca, capAB, A, N);
        bn_stats<<<256, blk, 0, stream>>>(A, N, st0);
        bn_apply<<<512, blk, 0, stream>>>(A, st0, g0, b0, nullptr, nullptr, t_bf, N, 1);

        // conv1_2 (rb_b, 64->64) -> A, carries pool reserve third 1
        hipMemsetAsync(A, 0, fbytes, stream);
        spconv_slot<64, false><<<dim3((unsigned)(cb + rsvBlocks(0, s1))), blk, 0, stream>>>(
            t_bf, W12f, rb_b_in, rb_b_out, pos_b, P, 0, Ka, tilesPerK, wavesPerK, TPW, capAB, yslot, A,
            cb, rb_p_out, 0, s1, Cp, pos_p, 2, M, k1, k2, k3);
        reduce_slot<false><<<gRows(N), blk, 0, stream>>>(yslot, Cb, capAB, A, N);
        bn_stats<<<256, blk, 0, stream>>>(A, N, st1);
        bn_apply<<<512, blk, 0, stream>>>(A, st1, g02, b02, nullptr, nullptr, B_bf, N, 1);

        // conv2 (rb_b, 32->64) -> A, carries pool reserve third 2
        hipMemsetAsync(A, 0, fbytes, stream);
        spconv_slot<32, false><<<dim3((unsigned)(cb + rsvBlocks(s1, s2))), blk, 0, stream>>>(
            x_bf, W2f, rb_b_in, rb_b_out, pos_b, P, 0, Ka, tilesPerK, wavesPerK, TPW, capAB, yslot, A,
            cb, rb_p_out, s1, s2, Cp, pos_p, 2, M, k1, k2, k3);
        reduce_slot<false><<<gRows(N), blk, 0, stream>>>(yslot, Cb, capAB, A, N);
        bn_stats<<<256, blk, 0, stream>>>(A, N, st2);
        bn_apply<<<512, blk, 0, stream>>>(A, st2, g1, b1, nullptr, nullptr, t_bf, N, 1);

        // conv3 (rb_a, 64->64) -> A, carries pool reserve third 3
        hipMemsetAsync(A, 0, fbytes, stream);
        spconv_slot<64, false><<<dim3((unsigned)(cb + rsvBlocks(s2, Ep))), blk, 0, stream>>>(
            t_bf, W3f, rb_a_in, rb_a_out, pos_a, P, 0, Ka, tilesPerK, wavesPerK, TPW, capAB, yslot, A,
            cb, rb_p_out, s2, Ep, Cp, pos_p, 2, M, k1, k2, k3);
        reduce_slot<false><<<gRows(N), blk, 0, stream>>>(yslot, Ca, capAB, A, N);
        bn_stats<<<256, blk, 0, stream>>>(A, N, st3);
        bn_apply<<<512, blk, 0, stream>>>(A, st3, g2, b2, B_bf, resA, t_bf, N, 1);

        // pool conv (rb_p, 64->64), 4 k-chunks reusing y window -> resB (true)
        hipMemsetAsync(resB, 0, (size_t)M * 64 * sizeof(float), stream);
        const int kc[5] = {0, k1, k2, k3, Kp};
        for (int c = 0; c < 4; ++c) {
            const int pcb = nConvBlocks(kc[c + 1] - kc[c]);
            spconv_slot<64, true><<<dim3((unsigned)pcb), blk, 0, stream>>>(
                t_bf, Wpf, rb_p_in, rb_p_out, pos_p, P, kc[c], kc[c + 1], tilesPerK, wavesPerK, TPW, capP, yslot, resB,
                pcb, nullptr, 0, 0, nullptr, nullptr, 0, 0, 0, 0, 0);
            reduce_slot<true><<<gRows(M), blk, 0, stream>>>(yslot, Cp + c * M, capP, resB, M);
        }
    } else {
        // -------- atomic fallback (true space everywhere) --------
        const int TPW2 = 16;
        const int wPK = (tilesPerK + TPW2 - 1) / TPW2;
        auto cblocks = [&](int K) { return dim3((unsigned)((K * wPK + 3) / 4)); };
        float* st = stats;

        hipMemsetAsync(A, 0, fbytes, stream);
        spconv_mfma<32><<<cblocks(Ka), blk, 0, stream>>>(x_bf, W1b, rb_a_in, rb_a_out, P, tilesPerK, wPK, Ka, TPW2, A);
        bn_stats<<<256, blk, 0, stream>>>(A, N, st);
        bn_apply<<<512, blk, 0, stream>>>(A, st, g0, b0, nullptr, nullptr, t_bf, N, 0);

        hipMemsetAsync(A, 0, fbytes, stream);
        spconv_mfma<64><<<cblocks(Ka), blk, 0, stream>>>(t_bf, W12b, rb_b_in, rb_b_out, P, tilesPerK, wPK, Ka, TPW2, A);
        bn_stats<<<256, blk, 0, stream>>>(A, N, st + 128);
        bn_apply<<<512, blk, 0, stream>>>(A, st + 128, g02, b02, nullptr, nullptr, B_bf, N, 0);

        hipMemsetAsync(A, 0, fbytes, stream);
        spconv_mfma<32><<<cblocks(Ka), blk, 0, stream>>>(x_bf, W2b, rb_b_in, rb_b_out, P, tilesPerK, wPK, Ka, TPW2, A);
        bn_stats<<<256, blk, 0, stream>>>(A, N, st + 256);
        bn_apply<<<512, blk, 0, stream>>>(A, st + 256, g1, b1, nullptr, nullptr, t_bf, N, 0);

        hipMemsetAsync(resA, 0, fbytes, stream);
        spconv_mfma<64><<<cblocks(Ka), blk, 0, stream>>>(t_bf, W3b, rb_a_in, rb_a_out, P, tilesPerK, wPK, Ka, TPW2, resA);
        bn_stats<<<256, blk, 0, stream>>>(resA, N, st + 384);
        bn_apply<<<512, blk, 0, stream>>>(resA, st + 384, g2, b2, B_bf, resA, t_bf, N, 0);

        hipMemsetAsync(resB, 0, (size_t)M * 64 * sizeof(float), stream);
        spconv_mfma<64><<<cblocks(Kp), blk, 0, stream>>>(t_bf, Wpb, rb_p_in, rb_p_out, P, tilesPerK, wPK, Kp, TPW2, resB);
    }
}